// Round 1
// baseline (412.521 us; speedup 1.0000x reference)
//
#include <hip/hip_runtime.h>

#define S_DIM 4
#define A_DIM 64
#define B_DIM 2048
#define D_DIM 384
#define H1D 128
#define H2D 128
#define H3D 64
#define MT 64   // batch rows per block

typedef __attribute__((ext_vector_type(8))) short short8;
typedef __attribute__((ext_vector_type(4))) float float4v;

__device__ __forceinline__ unsigned short f2bf(float f) {
  unsigned u = __float_as_uint(f);
  u += 0x7FFFu + ((u >> 16) & 1u);   // round-to-nearest-even
  return (unsigned short)(u >> 16);
}

// One-time (per launch) weight convert + transpose to bf16, N-major:
// W0T[s][h][d], W1T[s][h2][h1], W2T[s][h3][h2]. Coalesced reads, scattered 2B writes (tiny).
__global__ void prep_weights(const float* __restrict__ W0,
                             const float* __restrict__ W1,
                             const float* __restrict__ W2,
                             unsigned short* __restrict__ W0T,
                             unsigned short* __restrict__ W1T,
                             unsigned short* __restrict__ W2T) {
  int i = blockIdx.x * blockDim.x + threadIdx.x;
  if (i < S_DIM * D_DIM * H1D) {
    int h = i % H1D; int sd = i / H1D; int d = sd % D_DIM; int s = sd / D_DIM;
    W0T[((s * H1D) + h) * D_DIM + d] = f2bf(W0[i]);
  }
  if (i < S_DIM * H1D * H2D) {
    int h2 = i % H2D; int sh = i / H2D; int h1 = sh % H1D; int s = sh / H1D;
    W1T[((s * H2D) + h2) * H1D + h1] = f2bf(W1[i]);
  }
  if (i < S_DIM * H2D * H3D) {
    int h3 = i % H3D; int sh = i / H3D; int h2 = sh % H2D; int s = sh / H2D;
    W2T[((s * H3D) + h3) * H2D + h2] = f2bf(W2[i]);
  }
}

__global__ __launch_bounds__(256) void mlp_fused(
    const float* __restrict__ x, const int* __restrict__ species,
    const unsigned short* __restrict__ W0T, const unsigned short* __restrict__ W1T,
    const unsigned short* __restrict__ W2T,
    const float* __restrict__ b0, const float* __restrict__ b1,
    const float* __restrict__ b2, const float* __restrict__ W3,
    const float* __restrict__ b3, float* __restrict__ out) {
  // +8 bf16 pad -> row stride 272B: 16B-aligned for ds_read_b128, 2-way-max bank aliasing (free)
  __shared__ __align__(16) unsigned short H0s[MT][136];
  __shared__ __align__(16) unsigned short H1s[MT][136];
  __shared__ float H2s[MT][69];   // +1 pad: layer-3 scalar reads conflict-light

  const int a = blockIdx.y;
  const int brow0 = blockIdx.x * MT;
  const int sp = species[a];
  const int tid = threadIdx.x;
  const int wave = tid >> 6;
  const int lane = tid & 63;
  const int q = lane >> 4;        // quad: k = q*8+j (A/B), row = q*4+i (C/D)
  const int r = lane & 15;        // A row / B col / C col
  const int rb = wave * 16;       // this wave's 16 rows, all layers

  float4v zero = {0.f, 0.f, 0.f, 0.f};

  // ---------- layer 0: [16x384] @ [384x128] per wave ----------
  float4v c0[8];
#pragma unroll
  for (int n = 0; n < 8; ++n) c0[n] = zero;

  const float* xrow = x + ((size_t)(brow0 + rb + r) * A_DIM + a) * D_DIM + q * 8;
  const unsigned short* w0p = W0T + (size_t)sp * H1D * D_DIM + r * D_DIM + q * 8;
#pragma unroll 4
  for (int k0 = 0; k0 < D_DIM; k0 += 32) {
    float4v xa = *(const float4v*)(xrow + k0);
    float4v xb = *(const float4v*)(xrow + k0 + 4);
    short8 af;
    af[0] = (short)f2bf(xa[0]); af[1] = (short)f2bf(xa[1]);
    af[2] = (short)f2bf(xa[2]); af[3] = (short)f2bf(xa[3]);
    af[4] = (short)f2bf(xb[0]); af[5] = (short)f2bf(xb[1]);
    af[6] = (short)f2bf(xb[2]); af[7] = (short)f2bf(xb[3]);
    short8 bf[8];
#pragma unroll
    for (int n = 0; n < 8; ++n)
      bf[n] = *(const short8*)(w0p + n * 16 * D_DIM + k0);
#pragma unroll
    for (int n = 0; n < 8; ++n)
      c0[n] = __builtin_amdgcn_mfma_f32_16x16x32_bf16(af, bf[n], c0[n], 0, 0, 0);
  }
  {
    const float* b0p = b0 + sp * H1D;
#pragma unroll
    for (int n = 0; n < 8; ++n) {
      float bias = b0p[n * 16 + r];
#pragma unroll
      for (int i = 0; i < 4; ++i) {
        float y = c0[n][i] + bias;
        H0s[rb + q * 4 + i][n * 16 + r] = f2bf(__expf(-y * y));
      }
    }
  }
  // no __syncthreads needed: each wave reads only rows it wrote

  // ---------- layer 1: [16x128] @ [128x128] ----------
  float4v c1[8];
#pragma unroll
  for (int n = 0; n < 8; ++n) c1[n] = zero;
  const unsigned short* w1p = W1T + sp * H2D * H1D + r * H1D + q * 8;
#pragma unroll
  for (int k0 = 0; k0 < H1D; k0 += 32) {
    short8 af = *(const short8*)&H0s[rb + r][k0 + q * 8];
    short8 bf[8];
#pragma unroll
    for (int n = 0; n < 8; ++n)
      bf[n] = *(const short8*)(w1p + n * 16 * H1D + k0);
#pragma unroll
    for (int n = 0; n < 8; ++n)
      c1[n] = __builtin_amdgcn_mfma_f32_16x16x32_bf16(af, bf[n], c1[n], 0, 0, 0);
  }
  {
    const float* b1p = b1 + sp * H2D;
#pragma unroll
    for (int n = 0; n < 8; ++n) {
      float bias = b1p[n * 16 + r];
#pragma unroll
      for (int i = 0; i < 4; ++i) {
        float y = c1[n][i] + bias;
        H1s[rb + q * 4 + i][n * 16 + r] = f2bf(__expf(-y * y));
      }
    }
  }

  // ---------- layer 2: [16x128] @ [128x64] ----------
  float4v c2[4];
#pragma unroll
  for (int n = 0; n < 4; ++n) c2[n] = zero;
  const unsigned short* w2p = W2T + sp * H3D * H2D + r * H2D + q * 8;
#pragma unroll
  for (int k0 = 0; k0 < H2D; k0 += 32) {
    short8 af = *(const short8*)&H1s[rb + r][k0 + q * 8];
    short8 bf[4];
#pragma unroll
    for (int n = 0; n < 4; ++n)
      bf[n] = *(const short8*)(w2p + n * 16 * H2D + k0);
#pragma unroll
    for (int n = 0; n < 4; ++n)
      c2[n] = __builtin_amdgcn_mfma_f32_16x16x32_bf16(af, bf[n], c2[n], 0, 0, 0);
  }
  {
    const float* b2p = b2 + sp * H3D;
#pragma unroll
    for (int n = 0; n < 4; ++n) {
      float bias = b2p[n * 16 + r];
#pragma unroll
      for (int i = 0; i < 4; ++i) {
        float y = c2[n][i] + bias;
        H2s[rb + q * 4 + i][n * 16 + r] = __expf(-y * y);  // keep fp32 for final dot
      }
    }
  }
  __syncthreads();  // layer 3 crosses wave row boundaries

  // ---------- layer 3: per-row dot with W3[64], sum over atoms via atomicAdd ----------
  if (tid < MT) {
    const float* w3p = W3 + sp * H3D;
    float s = 0.f;
#pragma unroll
    for (int j = 0; j < H3D; ++j) s += H2s[tid][j] * w3p[j];
    s += b3[sp];
    atomicAdd(&out[brow0 + tid], s);
  }
}

extern "C" void kernel_launch(void* const* d_in, const int* in_sizes, int n_in,
                              void* d_out, int out_size, void* d_ws, size_t ws_size,
                              hipStream_t stream) {
  const float* x       = (const float*)d_in[0];
  const int*   species = (const int*)d_in[1];
  const float* W0 = (const float*)d_in[2];
  const float* b0 = (const float*)d_in[3];
  const float* W1 = (const float*)d_in[4];
  const float* b1 = (const float*)d_in[5];
  const float* W2 = (const float*)d_in[6];
  const float* b2 = (const float*)d_in[7];
  const float* W3 = (const float*)d_in[8];
  const float* b3 = (const float*)d_in[9];
  float* out = (float*)d_out;

  unsigned short* W0T = (unsigned short*)d_ws;                 // 4*128*384 bf16
  unsigned short* W1T = W0T + S_DIM * H1D * D_DIM;             // 4*128*128
  unsigned short* W2T = W1T + S_DIM * H2D * H1D;               // 4*64*128

  hipMemsetAsync(d_out, 0, out_size * sizeof(float), stream);  // out is accumulated atomically

  int prep_n = S_DIM * D_DIM * H1D;
  prep_weights<<<dim3((prep_n + 255) / 256), dim3(256), 0, stream>>>(W0, W1, W2, W0T, W1T, W2T);

  mlp_fused<<<dim3(B_DIM / MT, A_DIM), dim3(256), 0, stream>>>(
      x, species, W0T, W1T, W2T, b0, b1, b2, W3, b3, out);
}

// Round 2
// 310.575 us; speedup vs baseline: 1.3283x; 1.3283x over previous
//
#include <hip/hip_runtime.h>

#define S_DIM 4
#define A_DIM 64
#define B_DIM 2048
#define D_DIM 384
#define H1D 128
#define H2D 128
#define H3D 64
#define MT 64   // batch rows per block

typedef __attribute__((ext_vector_type(8))) short short8;
typedef __attribute__((ext_vector_type(4))) float float4v;

__device__ __forceinline__ unsigned short f2bf(float f) {
  unsigned u = __float_as_uint(f);
  u += 0x7FFFu + ((u >> 16) & 1u);   // round-to-nearest-even
  return (unsigned short)(u >> 16);
}

// LDS-tiled transpose + bf16 convert: coalesced reads AND coalesced writes.
// out layouts (N-major): W0T[s][h1][d], W1T[s][h2][h1], W2T[s][h3][h2]
__global__ __launch_bounds__(256) void prep_weights(
    const float* __restrict__ W0, const float* __restrict__ W1,
    const float* __restrict__ W2,
    unsigned short* __restrict__ W0T, unsigned short* __restrict__ W1T,
    unsigned short* __restrict__ W2T) {
  __shared__ float tile[32][33];
  int b = blockIdx.x;
  const float* src; unsigned short* dst; int R, C, dt, ht, s;
  if (b < 192) {                 // W0: 4 s x (384/32) x (128/32) = 192 tiles
    s = b / 48; int t = b % 48; dt = t / 4; ht = t % 4;
    src = W0 + s * D_DIM * H1D; dst = W0T + s * H1D * D_DIM; R = D_DIM; C = H1D;
  } else if (b < 256) {          // W1: 4 s x 4 x 4 = 64 tiles
    int bb = b - 192; s = bb / 16; int t = bb % 16; dt = t / 4; ht = t % 4;
    src = W1 + s * H1D * H2D; dst = W1T + s * H2D * H1D; R = H1D; C = H2D;
  } else {                       // W2: 4 s x 4 x 2 = 32 tiles
    int bb = b - 256; s = bb / 8; int t = bb % 8; dt = t / 2; ht = t % 2;
    src = W2 + s * H2D * H3D; dst = W2T + s * H3D * H2D; R = H2D; C = H3D;
  }
  int tx = threadIdx.x & 31, ty = threadIdx.x >> 5;
#pragma unroll
  for (int k = 0; k < 4; ++k)
    tile[ty + 8 * k][tx] = src[(size_t)(dt * 32 + ty + 8 * k) * C + ht * 32 + tx];
  __syncthreads();
#pragma unroll
  for (int k = 0; k < 4; ++k)
    dst[(size_t)(ht * 32 + ty + 8 * k) * R + dt * 32 + tx] = f2bf(tile[tx][ty + 8 * k]);
}

// Block = 1 atom x 64 batch rows. Wave w owns a 32-col (L0/L1) / 16-col (L2)
// output chunk for ALL 64 rows -> weight B-frags are short-lived registers,
// inner loops are pure ds_read_b128 -> MFMA.
__global__ __launch_bounds__(256, 3) void mlp_fused(
    const float* __restrict__ x, const int* __restrict__ species,
    const unsigned short* __restrict__ W0T, const unsigned short* __restrict__ W1T,
    const unsigned short* __restrict__ W2T,
    const float* __restrict__ b0, const float* __restrict__ b1,
    const float* __restrict__ b2, const float* __restrict__ W3,
    const float* __restrict__ b3, float* __restrict__ out) {
  // 136-short row stride (272B): 16B-aligned b128, balanced bank phases (verified R1: ~0 conflicts)
  __shared__ __align__(16) unsigned short xsH1[MT][136];  // x stage (L0), then H1 activations
  __shared__ __align__(16) unsigned short H0s[MT][136];
  __shared__ float H2s[MT][69];
  __shared__ float W3s[H3D];

  const int a = blockIdx.y;
  const int brow0 = blockIdx.x * MT;
  const int sp = species[a];
  const int tid = threadIdx.x;
  const int wave = tid >> 6;
  const int lane = tid & 63;
  const int q = lane >> 4;   // A/B k-quad, C/D row-quad
  const int r = lane & 15;   // A row / B col / C col

  if (tid < H3D) W3s[tid] = W3[sp * H3D + tid];

  const float4v zero = {0.f, 0.f, 0.f, 0.f};

  // x staging coords: thread t covers row (t>>2), 16B pieces at 64B stride
  const int srow = tid >> 2;
  const int c4 = tid & 3;
  const float* xrow = x + ((size_t)(brow0 + srow) * A_DIM + a) * D_DIM;

  // ---------------- layer 0: [64x384] @ [384x128], 3 k-stages of 128 ----------------
  float4v acc0[4][2];
#pragma unroll
  for (int g = 0; g < 4; ++g) { acc0[g][0] = zero; acc0[g][1] = zero; }
  const unsigned short* w0base = W0T + (size_t)sp * H1D * D_DIM + (wave * 32 + r) * D_DIM + q * 8;

#pragma unroll
  for (int st = 0; st < 3; ++st) {
    const int ks = st * 128;
    // B-frags for this stage (global->reg, L2-hot, hoistable above barrier)
    short8 bf[4][2];
#pragma unroll
    for (int kk = 0; kk < 4; ++kk)
#pragma unroll
      for (int n = 0; n < 2; ++n)
        bf[kk][n] = *(const short8*)(w0base + n * 16 * D_DIM + ks + kk * 32);
    // cooperative x stage: 64 rows x 128 cols fp32 -> bf16 LDS
    float4v xv[8];
#pragma unroll
    for (int j = 0; j < 8; ++j)
      xv[j] = *(const float4v*)(xrow + ks + c4 * 4 + j * 16);
    __syncthreads();   // previous stage fully consumed before overwrite
#pragma unroll
    for (int j = 0; j < 8; ++j) {
      unsigned short* p = &xsH1[srow][c4 * 4 + j * 16];
      p[0] = f2bf(xv[j][0]); p[1] = f2bf(xv[j][1]);
      p[2] = f2bf(xv[j][2]); p[3] = f2bf(xv[j][3]);
    }
    __syncthreads();
#pragma unroll
    for (int g = 0; g < 4; ++g)
#pragma unroll
      for (int kk = 0; kk < 4; ++kk) {
        short8 af = *(const short8*)&xsH1[g * 16 + r][kk * 32 + q * 8];
        acc0[g][0] = __builtin_amdgcn_mfma_f32_16x16x32_bf16(af, bf[kk][0], acc0[g][0], 0, 0, 0);
        acc0[g][1] = __builtin_amdgcn_mfma_f32_16x16x32_bf16(af, bf[kk][1], acc0[g][1], 0, 0, 0);
      }
  }
  __syncthreads();   // xsH1 reads done; H0s about to be written
  {
    const float* b0p = b0 + sp * H1D;
#pragma unroll
    for (int n = 0; n < 2; ++n) {
      float bias = b0p[wave * 32 + n * 16 + r];
#pragma unroll
      for (int g = 0; g < 4; ++g)
#pragma unroll
        for (int i = 0; i < 4; ++i) {
          float y = acc0[g][n][i] + bias;
          H0s[g * 16 + q * 4 + i][wave * 32 + n * 16 + r] = f2bf(__expf(-y * y));
        }
    }
  }
  __syncthreads();

  // ---------------- layer 1: [64x128] @ [128x128] ----------------
  float4v acc1[4][2];
#pragma unroll
  for (int g = 0; g < 4; ++g) { acc1[g][0] = zero; acc1[g][1] = zero; }
  {
    const unsigned short* w1base = W1T + (size_t)sp * H2D * H1D + (wave * 32 + r) * H1D + q * 8;
    short8 bf[4][2];
#pragma unroll
    for (int kk = 0; kk < 4; ++kk)
#pragma unroll
      for (int n = 0; n < 2; ++n)
        bf[kk][n] = *(const short8*)(w1base + n * 16 * H1D + kk * 32);
#pragma unroll
    for (int g = 0; g < 4; ++g)
#pragma unroll
      for (int kk = 0; kk < 4; ++kk) {
        short8 af = *(const short8*)&H0s[g * 16 + r][kk * 32 + q * 8];
        acc1[g][0] = __builtin_amdgcn_mfma_f32_16x16x32_bf16(af, bf[kk][0], acc1[g][0], 0, 0, 0);
        acc1[g][1] = __builtin_amdgcn_mfma_f32_16x16x32_bf16(af, bf[kk][1], acc1[g][1], 0, 0, 0);
      }
    const float* b1p = b1 + sp * H2D;
#pragma unroll
    for (int n = 0; n < 2; ++n) {
      float bias = b1p[wave * 32 + n * 16 + r];
#pragma unroll
      for (int g = 0; g < 4; ++g)
#pragma unroll
        for (int i = 0; i < 4; ++i) {
          float y = acc1[g][n][i] + bias;
          xsH1[g * 16 + q * 4 + i][wave * 32 + n * 16 + r] = f2bf(__expf(-y * y));
        }
    }
  }
  __syncthreads();

  // ---------------- layer 2: [64x128] @ [128x64] (wave owns 16 cols) ----------------
  {
    float4v acc2[4];
#pragma unroll
    for (int g = 0; g < 4; ++g) acc2[g] = zero;
    const unsigned short* w2base = W2T + (size_t)sp * H3D * H2D + (wave * 16 + r) * H2D + q * 8;
    short8 bf[4];
#pragma unroll
    for (int kk = 0; kk < 4; ++kk)
      bf[kk] = *(const short8*)(w2base + kk * 32);
#pragma unroll
    for (int g = 0; g < 4; ++g)
#pragma unroll
      for (int kk = 0; kk < 4; ++kk) {
        short8 af = *(const short8*)&xsH1[g * 16 + r][kk * 32 + q * 8];
        acc2[g] = __builtin_amdgcn_mfma_f32_16x16x32_bf16(af, bf[kk], acc2[g], 0, 0, 0);
      }
    float bias = b2[sp * H3D + wave * 16 + r];
#pragma unroll
    for (int g = 0; g < 4; ++g)
#pragma unroll
      for (int i = 0; i < 4; ++i) {
        float y = acc2[g][i] + bias;
        H2s[g * 16 + q * 4 + i][wave * 16 + r] = __expf(-y * y);
      }
  }
  __syncthreads();

  // ---------------- layer 3: dot with W3[64] + cross-atom atomic sum ----------------
  {
    const int row = tid >> 2;
    const int seg = tid & 3;
    float s = 0.f;
#pragma unroll
    for (int j = 0; j < 16; ++j)
      s += H2s[row][seg * 16 + j] * W3s[seg * 16 + j];
    s += __shfl_xor(s, 1);
    s += __shfl_xor(s, 2);
    if (seg == 0) atomicAdd(&out[brow0 + row], s + b3[sp]);
  }
}

extern "C" void kernel_launch(void* const* d_in, const int* in_sizes, int n_in,
                              void* d_out, int out_size, void* d_ws, size_t ws_size,
                              hipStream_t stream) {
  const float* x       = (const float*)d_in[0];
  const int*   species = (const int*)d_in[1];
  const float* W0 = (const float*)d_in[2];
  const float* b0 = (const float*)d_in[3];
  const float* W1 = (const float*)d_in[4];
  const float* b1 = (const float*)d_in[5];
  const float* W2 = (const float*)d_in[6];
  const float* b2 = (const float*)d_in[7];
  const float* W3 = (const float*)d_in[8];
  const float* b3 = (const float*)d_in[9];
  float* out = (float*)d_out;

  unsigned short* W0T = (unsigned short*)d_ws;
  unsigned short* W1T = W0T + S_DIM * H1D * D_DIM;
  unsigned short* W2T = W1T + S_DIM * H2D * H1D;

  hipMemsetAsync(d_out, 0, out_size * sizeof(float), stream);
  prep_weights<<<dim3(288), dim3(256), 0, stream>>>(W0, W1, W2, W0T, W1T, W2T);
  mlp_fused<<<dim3(B_DIM / MT, A_DIM), dim3(256), 0, stream>>>(
      x, species, W0T, W1T, W2T, b0, b1, b2, W3, b3, out);
}